// Round 4
// baseline (473.544 us; speedup 1.0000x reference)
//
#include <hip/hip_runtime.h>
#include <math.h>

// Problem constants
#define BB 4
#define SS 2048
#define DD 1024
#define HH 2048
#define AD 128
#define EE 8
#define MM (BB*SS)   // 8192
#define PS 136       // padded LDS row stride (u16) for 128-wide tiles: 16B-aligned rows, 2-way-max banks

typedef unsigned short u16;
typedef short bf16x8 __attribute__((ext_vector_type(8)));
typedef float f32x4 __attribute__((ext_vector_type(4)));

__device__ __forceinline__ float silu_f(float x){ return x / (1.f + __expf(-x)); }

__device__ __forceinline__ u16 f2bf(float f){
    union { float f; unsigned u; } c; c.f = f;
    unsigned r = (c.u + 0x7FFFu + ((c.u >> 16) & 1u)) >> 16;
    return (u16)r;
}

// async global->LDS, 16B per lane. LDS dest must be wave-uniform base + lane*16.
__device__ __forceinline__ void gld16(const u16* g, u16* l){
    __builtin_amdgcn_global_load_lds((const __attribute__((address_space(1))) void*)g,
                                     (__attribute__((address_space(3))) void*)l, 16, 0, 0);
}

// ---------------------------------------------------------------------------
// Split-K NT GEMM, N fixed = 128. grid = (S, M/128, Z).
// P offset = s*sSplit + z*sC.
// ---------------------------------------------------------------------------
__global__ __launch_bounds__(256,2) void mfma_sk(
    const u16* __restrict__ A, const u16* __restrict__ B, float* __restrict__ P,
    int M, int K, int S, long sA, long sB, long sC, long sSplit)
{
    __shared__ __align__(16) u16 As[128*32];
    __shared__ __align__(16) u16 Bs[128*32];
    const int t = threadIdx.x;
    const int lane = t & 63;
    const int wv = t >> 6;
    const int s = blockIdx.x;
    const int m0 = blockIdx.y * 128;
    const u16* Ab = A + (long)blockIdx.z * sA;
    const u16* Bb = B + (long)blockIdx.z * sB;
    const int srow = t >> 2, scol = (t & 3) * 8;
    const int Ks = K / S, kBeg = s * Ks;
    const u16* ga0 = Ab + (long)(m0 + srow) * K + scol + kBeg;
    const u16* ga1 = ga0 + 64L * K;
    const u16* gb0 = Bb + (long)srow * K + scol + kBeg;
    const u16* gb1 = gb0 + 64L * K;
    u16* la0 = As + t * 8;  u16* la1 = As + 2048 + t * 8;
    u16* lb0 = Bs + t * 8;  u16* lb1 = Bs + 2048 + t * 8;
    const int fr = lane & 15, q = lane >> 4;
    const int wm = (wv & 1) * 64, wn = (wv >> 1) * 64;

    f32x4 acc[4][4] = {};
    for (int k0 = 0; k0 < Ks; k0 += 32) {
        gld16(ga0 + k0, la0);
        gld16(ga1 + k0, la1);
        gld16(gb0 + k0, lb0);
        gld16(gb1 + k0, lb1);
        __syncthreads();
        bf16x8 af[4], bfr[4];
        #pragma unroll
        for (int i = 0; i < 4; ++i) af[i]  = *(const bf16x8*)&As[(wm + i*16 + fr)*32 + q*8];
        #pragma unroll
        for (int i = 0; i < 4; ++i) bfr[i] = *(const bf16x8*)&Bs[(wn + i*16 + fr)*32 + q*8];
        #pragma unroll
        for (int mi = 0; mi < 4; ++mi)
            #pragma unroll
            for (int ni = 0; ni < 4; ++ni)
                acc[mi][ni] = __builtin_amdgcn_mfma_f32_16x16x32_bf16(af[mi], bfr[ni], acc[mi][ni], 0, 0, 0);
        __syncthreads();
    }

    float* Pf = P + (long)s * sSplit + (long)blockIdx.z * sC;
    #pragma unroll
    for (int mi = 0; mi < 4; ++mi)
        #pragma unroll
        for (int ni = 0; ni < 4; ++ni) {
            const int col = wn + ni*16 + fr;
            #pragma unroll
            for (int r = 0; r < 4; ++r) {
                const int row = m0 + wm + mi*16 + q*4 + r;
                Pf[(long)row * 128 + col] = acc[mi][ni][r];
            }
        }
}

// ---------------------------------------------------------------------------
// Fused up/gate: H[M,HH] = bf16( silu(X@Wg^T+bg) * (X@Wu^T+bu) ). 128x128 tile.
// ---------------------------------------------------------------------------
__global__ __launch_bounds__(256,2) void mfma_upgate(
    const u16* __restrict__ X, const u16* __restrict__ Wu_, const u16* __restrict__ Wg_,
    const float* __restrict__ bu, const float* __restrict__ bg, u16* __restrict__ H)
{
    __shared__ __align__(16) u16 Xs[128*32];
    __shared__ __align__(16) u16 Us[128*32];
    __shared__ __align__(16) u16 Gs[128*32];
    const int t = threadIdx.x, lane = t & 63, wv = t >> 6;
    const int m0 = blockIdx.y * 128, n0 = blockIdx.x * 128;
    const int srow = t >> 2, scol = (t & 3) * 8;
    const u16* gx0 = X   + (long)(m0 + srow) * DD + scol;
    const u16* gx1 = gx0 + 64L * DD;
    const u16* gu0 = Wu_ + (long)(n0 + srow) * DD + scol;
    const u16* gu1 = gu0 + 64L * DD;
    const u16* gg0 = Wg_ + (long)(n0 + srow) * DD + scol;
    const u16* gg1 = gg0 + 64L * DD;
    const int fr = lane & 15, q = lane >> 4;
    const int wm = (wv & 1) * 64, wn = (wv >> 1) * 64;

    f32x4 accu[4][4] = {};
    f32x4 accg[4][4] = {};
    for (int k0 = 0; k0 < DD; k0 += 32) {
        gld16(gx0 + k0, Xs + t*8);
        gld16(gx1 + k0, Xs + 2048 + t*8);
        gld16(gu0 + k0, Us + t*8);
        gld16(gu1 + k0, Us + 2048 + t*8);
        gld16(gg0 + k0, Gs + t*8);
        gld16(gg1 + k0, Gs + 2048 + t*8);
        __syncthreads();
        bf16x8 xf[4], uf[4], gf[4];
        #pragma unroll
        for (int i = 0; i < 4; ++i) {
            xf[i] = *(const bf16x8*)&Xs[(wm + i*16 + fr)*32 + q*8];
            uf[i] = *(const bf16x8*)&Us[(wn + i*16 + fr)*32 + q*8];
            gf[i] = *(const bf16x8*)&Gs[(wn + i*16 + fr)*32 + q*8];
        }
        #pragma unroll
        for (int mi = 0; mi < 4; ++mi)
            #pragma unroll
            for (int ni = 0; ni < 4; ++ni) {
                accu[mi][ni] = __builtin_amdgcn_mfma_f32_16x16x32_bf16(xf[mi], uf[ni], accu[mi][ni], 0, 0, 0);
                accg[mi][ni] = __builtin_amdgcn_mfma_f32_16x16x32_bf16(xf[mi], gf[ni], accg[mi][ni], 0, 0, 0);
            }
        __syncthreads();
    }
    #pragma unroll
    for (int mi = 0; mi < 4; ++mi) {
        #pragma unroll
        for (int ni = 0; ni < 4; ++ni) {
            const int col = n0 + wn + ni*16 + fr;
            #pragma unroll
            for (int r = 0; r < 4; ++r) {
                const int row = m0 + wm + mi*16 + q*4 + r;
                const float u = accu[mi][ni][r] + bu[col];
                const float g = accg[mi][ni][r] + bg[col];
                H[(long)row * HH + col] = f2bf(silu_f(g) * u);
            }
        }
    }
}

// ---------------------------------------------------------------------------
// Final: out = sumw*(hidden@Wd^T + bd) + 0.1*(acat@Wcat^T). 128x128 tile.
// K1 = 2048 (hidden,Wd ld 2048), K2 = 256 (acat,Wcat ld 256).
// ---------------------------------------------------------------------------
__global__ __launch_bounds__(256,2) void mfma_final(
    const u16* __restrict__ Hh, const u16* __restrict__ Wd_,
    const u16* __restrict__ Ac, const u16* __restrict__ Wcat,
    const float* __restrict__ bd, const float* __restrict__ sumw,
    float* __restrict__ out)
{
    __shared__ __align__(16) u16 As[128*32];
    __shared__ __align__(16) u16 Bs[128*32];
    const int t = threadIdx.x, lane = t & 63, wv = t >> 6;
    const int m0 = blockIdx.y * 128, n0 = blockIdx.x * 128;
    const int srow = t >> 2, scol = (t & 3) * 8;
    const int fr = lane & 15, q = lane >> 4;
    const int wm = (wv & 1) * 64, wn = (wv >> 1) * 64;
    u16* la0 = As + t * 8;  u16* la1 = As + 2048 + t * 8;
    u16* lb0 = Bs + t * 8;  u16* lb1 = Bs + 2048 + t * 8;

    f32x4 acc[4][4] = {};
    {
        const u16* ga0 = Hh  + (long)(m0 + srow) * HH + scol;
        const u16* ga1 = ga0 + 64L * HH;
        const u16* gb0 = Wd_ + (long)(n0 + srow) * HH + scol;
        const u16* gb1 = gb0 + 64L * HH;
        for (int k0 = 0; k0 < HH; k0 += 32) {
            gld16(ga0 + k0, la0);
            gld16(ga1 + k0, la1);
            gld16(gb0 + k0, lb0);
            gld16(gb1 + k0, lb1);
            __syncthreads();
            bf16x8 af[4], bfr[4];
            #pragma unroll
            for (int i = 0; i < 4; ++i) af[i]  = *(const bf16x8*)&As[(wm + i*16 + fr)*32 + q*8];
            #pragma unroll
            for (int i = 0; i < 4; ++i) bfr[i] = *(const bf16x8*)&Bs[(wn + i*16 + fr)*32 + q*8];
            #pragma unroll
            for (int mi = 0; mi < 4; ++mi)
                #pragma unroll
                for (int ni = 0; ni < 4; ++ni)
                    acc[mi][ni] = __builtin_amdgcn_mfma_f32_16x16x32_bf16(af[mi], bfr[ni], acc[mi][ni], 0, 0, 0);
            __syncthreads();
        }
    }
    f32x4 acc2[4][4] = {};
    {
        const u16* ga0 = Ac   + (long)(m0 + srow) * 256 + scol;
        const u16* ga1 = ga0 + 64L * 256;
        const u16* gb0 = Wcat + (long)(n0 + srow) * 256 + scol;
        const u16* gb1 = gb0 + 64L * 256;
        for (int k0 = 0; k0 < 256; k0 += 32) {
            gld16(ga0 + k0, la0);
            gld16(ga1 + k0, la1);
            gld16(gb0 + k0, lb0);
            gld16(gb1 + k0, lb1);
            __syncthreads();
            bf16x8 af[4], bfr[4];
            #pragma unroll
            for (int i = 0; i < 4; ++i) af[i]  = *(const bf16x8*)&As[(wm + i*16 + fr)*32 + q*8];
            #pragma unroll
            for (int i = 0; i < 4; ++i) bfr[i] = *(const bf16x8*)&Bs[(wn + i*16 + fr)*32 + q*8];
            #pragma unroll
            for (int mi = 0; mi < 4; ++mi)
                #pragma unroll
                for (int ni = 0; ni < 4; ++ni)
                    acc2[mi][ni] = __builtin_amdgcn_mfma_f32_16x16x32_bf16(af[mi], bfr[ni], acc2[mi][ni], 0, 0, 0);
            __syncthreads();
        }
    }
    #pragma unroll
    for (int mi = 0; mi < 4; ++mi)
        #pragma unroll
        for (int ni = 0; ni < 4; ++ni) {
            const int col = n0 + wn + ni*16 + fr;
            #pragma unroll
            for (int r = 0; r < 4; ++r) {
                const int row = m0 + wm + mi*16 + q*4 + r;
                out[(long)row * DD + col] =
                    sumw[row] * (acc[mi][ni][r] + bd[col]) + 0.1f * acc2[mi][ni][r];
            }
        }
}

// ---------------------------------------------------------------------------
// Fused expert branch: per 128-row block, for e in 0..7:
//   h = pre@A[e]^T (MFMA, frags direct from global), LN rows (shfl), weighted sum.
// Writes acat[:,0:128] (bf16) and sumw. Wave wv owns rows wm=wv*32..+31 (full N).
// ---------------------------------------------------------------------------
__global__ __launch_bounds__(256,1) void expert_fused(
    const u16* __restrict__ pre, const u16* __restrict__ aexp,
    const float* __restrict__ ew, const float* __restrict__ eg,
    const float* __restrict__ eb, u16* __restrict__ acat,
    float* __restrict__ sumw)
{
    __shared__ float ewsh[128*8];
    __shared__ float egsh[8*128], ebsh[8*128];
    const int t = threadIdx.x, lane = t & 63, wv = t >> 6;
    const int fr = lane & 15, q = lane >> 4;
    const int wm = wv * 32;
    const int m0 = blockIdx.x * 128;
    {   const int row = t >> 1, j = (t & 1)*4;
        *(float4*)&ewsh[row*8+j] = *(const float4*)&ew[(long)(m0+row)*EE + j]; }
    {   const int e = t >> 5, c = (t & 31)*4;
        *(float4*)&egsh[e*128+c] = *(const float4*)&eg[e*128+c];
        *(float4*)&ebsh[e*128+c] = *(const float4*)&eb[e*128+c]; }
    __syncthreads();

    f32x4 hwacc[2][8] = {};
    for (int e = 0; e < EE; ++e) {
        f32x4 acc[2][8] = {};
        const u16* Ae = aexp + (long)e * AD * AD;
        #pragma unroll
        for (int ks = 0; ks < 4; ++ks) {
            bf16x8 af[2], bfr[8];
            #pragma unroll
            for (int mi = 0; mi < 2; ++mi)
                af[mi] = *(const bf16x8*)&pre[(long)(m0 + wm + mi*16 + fr)*AD + ks*32 + q*8];
            #pragma unroll
            for (int ni = 0; ni < 8; ++ni)
                bfr[ni] = *(const bf16x8*)&Ae[(long)(ni*16 + fr)*AD + ks*32 + q*8];
            #pragma unroll
            for (int mi = 0; mi < 2; ++mi)
                #pragma unroll
                for (int ni = 0; ni < 8; ++ni)
                    acc[mi][ni] = __builtin_amdgcn_mfma_f32_16x16x32_bf16(af[mi], bfr[ni], acc[mi][ni], 0, 0, 0);
        }
        #pragma unroll
        for (int mi = 0; mi < 2; ++mi)
            #pragma unroll
            for (int r = 0; r < 4; ++r) {
                float s = 0.f, s2 = 0.f;
                #pragma unroll
                for (int ni = 0; ni < 8; ++ni) { const float v = acc[mi][ni][r]; s += v; s2 += v*v; }
                #pragma unroll
                for (int msk = 1; msk < 16; msk <<= 1) {
                    s  += __shfl_xor(s,  msk, 64);
                    s2 += __shfl_xor(s2, msk, 64);
                }
                const float mean = s * (1.f/128.f);
                const float var  = s2 * (1.f/128.f) - mean*mean;
                const float rs   = rsqrtf(var + 1e-5f);
                const int rowl = wm + mi*16 + q*4 + r;
                float w = ewsh[rowl*8 + e]; w = w > 0.f ? w : 0.f;
                #pragma unroll
                for (int ni = 0; ni < 8; ++ni) {
                    const int col = ni*16 + fr;
                    hwacc[mi][ni][r] += w * ((acc[mi][ni][r] - mean) * rs * egsh[e*128+col] + ebsh[e*128+col]);
                }
            }
    }
    #pragma unroll
    for (int mi = 0; mi < 2; ++mi)
        #pragma unroll
        for (int r = 0; r < 4; ++r) {
            const int rowl = wm + mi*16 + q*4 + r;
            #pragma unroll
            for (int ni = 0; ni < 8; ++ni)
                acat[(long)(m0+rowl)*256 + ni*16 + fr] = f2bf(hwacc[mi][ni][r]);
            if (fr == 0) {
                float sw = 0.f;
                #pragma unroll
                for (int j = 0; j < 8; ++j) sw += ewsh[rowl*8 + j];
                sumw[m0 + rowl] = sw;
            }
        }
}

// ---------------------------------------------------------------------------
// Flash attention-like block: per (64-row Q-tile, batch):
//   loop T-tiles: S = Q@ao_t^T -> silu(clip) -> Ps (LDS) -> vacc += P@aiT_t^T.
// Epilogue: acat[:,128:256] = bf16(sumw[row] * vacc). B-frags direct global.
// ---------------------------------------------------------------------------
__global__ __launch_bounds__(256,2) void flash_adapt(
    const u16* __restrict__ ai, const u16* __restrict__ ao,
    const u16* __restrict__ aiT, const float* __restrict__ sumw,
    u16* __restrict__ acat)
{
    __shared__ __align__(16) u16 Psh[64*PS];
    const int t = threadIdx.x, lane = t & 63, wv = t >> 6;
    const int fr = lane & 15, q = lane >> 4;
    const int wm = (wv & 1) * 32, wn = (wv >> 1) * 64;
    const int b = blockIdx.y, q0 = blockIdx.x * 64;
    const u16* aib  = ai  + (long)b * SS * AD;
    const u16* aob  = ao  + (long)b * SS * AD;
    const u16* aiTb = aiT + (long)b * AD * SS;

    bf16x8 qf[2][4];
    #pragma unroll
    for (int mi = 0; mi < 2; ++mi)
        #pragma unroll
        for (int ks = 0; ks < 4; ++ks)
            qf[mi][ks] = *(const bf16x8*)&aib[(long)(q0 + wm + mi*16 + fr)*AD + ks*32 + q*8];

    f32x4 vacc[2][4] = {};
    for (int tt = 0; tt < SS; tt += 128) {
        f32x4 acc[2][4] = {};
        #pragma unroll
        for (int ks = 0; ks < 4; ++ks) {
            bf16x8 bo[4];
            #pragma unroll
            for (int ni = 0; ni < 4; ++ni)
                bo[ni] = *(const bf16x8*)&aob[(long)(tt + wn + ni*16 + fr)*AD + ks*32 + q*8];
            #pragma unroll
            for (int mi = 0; mi < 2; ++mi)
                #pragma unroll
                for (int ni = 0; ni < 4; ++ni)
                    acc[mi][ni] = __builtin_amdgcn_mfma_f32_16x16x32_bf16(qf[mi][ks], bo[ni], acc[mi][ni], 0, 0, 0);
        }
        __syncthreads();   // previous iteration's Ps reads complete
        #pragma unroll
        for (int mi = 0; mi < 2; ++mi)
            #pragma unroll
            for (int ni = 0; ni < 4; ++ni)
                #pragma unroll
                for (int r = 0; r < 4; ++r) {
                    float v = acc[mi][ni][r];
                    v = fminf(fmaxf(v, -5.f), 5.f);
                    Psh[(wm + mi*16 + q*4 + r)*PS + wn + ni*16 + fr] = f2bf(silu_f(v));
                }
        __syncthreads();
        #pragma unroll
        for (int ks = 0; ks < 4; ++ks) {
            bf16x8 pf[2], bi[4];
            #pragma unroll
            for (int mi = 0; mi < 2; ++mi)
                pf[mi] = *(const bf16x8*)&Psh[(wm + mi*16 + fr)*PS + ks*32 + q*8];
            #pragma unroll
            for (int ni = 0; ni < 4; ++ni)
                bi[ni] = *(const bf16x8*)&aiTb[(long)(wn + ni*16 + fr)*SS + tt + ks*32 + q*8];
            #pragma unroll
            for (int mi = 0; mi < 2; ++mi)
                #pragma unroll
                for (int ni = 0; ni < 4; ++ni)
                    vacc[mi][ni] = __builtin_amdgcn_mfma_f32_16x16x32_bf16(pf[mi], bi[ni], vacc[mi][ni], 0, 0, 0);
        }
    }
    #pragma unroll
    for (int mi = 0; mi < 2; ++mi)
        #pragma unroll
        for (int r = 0; r < 4; ++r) {
            const long grow = (long)b * SS + q0 + wm + mi*16 + q*4 + r;
            const float sw = sumw[grow];
            #pragma unroll
            for (int ni = 0; ni < 4; ++ni)
                acat[grow*256 + 128 + wn + ni*16 + fr] = f2bf(sw * vacc[mi][ni][r]);
        }
}

// ---------------------------------------------------------------------------
// Split-K reduce + bias + (optional raw bf16 out) + LayerNorm(128) -> bf16.
// ---------------------------------------------------------------------------
template<int S>
__global__ __launch_bounds__(128) void ln_reduce(
    const float* __restrict__ P, long sSplit, const float* __restrict__ bias,
    u16* __restrict__ raw, u16* __restrict__ ln_out,
    const float* __restrict__ g, const float* __restrict__ b)
{
    const int r = blockIdx.x, tid = threadIdx.x;
    float v = bias[tid];
    #pragma unroll
    for (int s = 0; s < S; ++s) v += P[(long)s * sSplit + (long)r * AD + tid];
    if (raw) raw[(long)r * AD + tid] = f2bf(v);
    __shared__ float red[AD], red2[AD];
    red[tid] = v; red2[tid] = v*v;
    __syncthreads();
    for (int s = 64; s > 0; s >>= 1) {
        if (tid < s) { red[tid] += red[tid+s]; red2[tid] += red2[tid+s]; }
        __syncthreads();
    }
    const float mean = red[0] * (1.f/AD);
    const float var  = red2[0] * (1.f/AD) - mean*mean;
    const float rs   = rsqrtf(var + 1e-5f);
    ln_out[(long)r * AD + tid] = f2bf((v - mean) * rs * g[tid] + b[tid]);
}

// Reduce wc partials (S=4, z=2) -> Wcat [1024, 256] bf16.
__global__ __launch_bounds__(256) void reduce_cat(
    const float* __restrict__ P, u16* __restrict__ Wcat)
{
    const int i = blockIdx.x * 256 + threadIdx.x;   // 65536 total
    const int a4 = i & 31, z = (i >> 5) & 1, d = i >> 6;
    const float* src = P + (long)z * (4L*DD*AD) + (long)d * AD + a4*4;
    float4 v = *(const float4*)src;
    #pragma unroll
    for (int s = 1; s < 4; ++s) {
        const float4 w = *(const float4*)(src + (long)s * DD * AD);
        v.x += w.x; v.y += w.y; v.z += w.z; v.w += w.w;
    }
    ushort4 o; o.x=f2bf(v.x); o.y=f2bf(v.y); o.z=f2bf(v.z); o.w=f2bf(v.w);
    ((ushort4*)Wcat)[(long)d*64 + z*32 + a4] = o;
}

// bf16 transpose: in [2048,128] -> out [128,2048], z-batched via strides.
__global__ __launch_bounds__(256) void transpose_bf(
    const u16* __restrict__ in, u16* __restrict__ out, long sIn, long sOut)
{
    __shared__ u16 tile[32][33];
    in  += (long)blockIdx.z * sIn;
    out += (long)blockIdx.z * sOut;
    const int x0 = blockIdx.x * 32, y0 = blockIdx.y * 32;
    const int tx = threadIdx.x & 31, ty = threadIdx.x >> 5;
    #pragma unroll
    for (int j = 0; j < 4; ++j)
        tile[ty + j*8][tx] = in[(long)(y0 + ty + j*8) * AD + x0 + tx];
    __syncthreads();
    #pragma unroll
    for (int j = 0; j < 4; ++j)
        out[(long)(x0 + ty + j*8) * SS + y0 + tx] = tile[tx][ty + j*8];
}

// Packed f32->bf16 convert: 5 segments, 4 elems/thread. cum[] in float4 units.
struct Cvt5 { const float* in[5]; u16* out[5]; long cum[6]; };
__global__ __launch_bounds__(256) void cvt_pack(Cvt5 a)
{
    const long i = (long)blockIdx.x * 256 + threadIdx.x;
    if (i >= a.cum[5]) return;
    int s = 0;
    while (i >= a.cum[s+1]) ++s;
    const long j = i - a.cum[s];
    const float4 v = ((const float4*)a.in[s])[j];
    ushort4 o;
    o.x = f2bf(v.x); o.y = f2bf(v.y); o.z = f2bf(v.z); o.w = f2bf(v.w);
    ((ushort4*)a.out[s])[j] = o;
}

extern "C" void kernel_launch(void* const* d_in, const int* in_sizes, int n_in,
                              void* d_out, int out_size, void* d_ws, size_t ws_size,
                              hipStream_t stream) {
    const float* x    = (const float*)d_in[0];
    const float* ew   = (const float*)d_in[1];
    const float* Wu   = (const float*)d_in[2];
    const float* bu   = (const float*)d_in[3];
    const float* Wg   = (const float*)d_in[4];
    const float* bg   = (const float*)d_in[5];
    const float* Wd   = (const float*)d_in[6];
    const float* bd   = (const float*)d_in[7];
    const float* Wpre = (const float*)d_in[8];
    const float* bpre = (const float*)d_in[9];
    const float* Wpost= (const float*)d_in[10];
    const float* bpost= (const float*)d_in[11];
    const float* ln_g = (const float*)d_in[12];
    const float* ln_b = (const float*)d_in[13];
    const float* Wap  = (const float*)d_in[14];
    const float* Aex  = (const float*)d_in[15];
    const float* eg   = (const float*)d_in[16];
    const float* eb   = (const float*)d_in[17];
    const float* Wp   = (const float*)d_in[18];
    const float* Wo   = (const float*)d_in[19];
    float* out = (float*)d_out;

    // ---- workspace layout (~96.5 MB) ----
    char* p = (char*)d_ws;
    auto take = [&](long bytes) -> char* {
        char* r = p; p += (bytes + 255) & ~255L; return r;
    };
    u16* x_slot  = (u16*)take(16777216);          // x_bf phase1; sub-slots phase2
    u16* wslot   = (u16*)take((long)2*DD*HH*2);   // 8MB: [Wu|Wg] then [Wo|Wd]
    u16* wpre    = (u16*)take((long)AD*DD*2);
    u16* aex     = (u16*)take((long)EE*AD*AD*2);
    u16* pre_bf  = (u16*)take((long)MM*AD*2);
    u16* ai_bf   = (u16*)take((long)MM*AD*2);
    char* shareA = take(33554432);                // preP (16MB) then wpostP (32MB)
    u16* acat    = (u16*)take((long)MM*256*2);    // [hw | sumw*adapt]
    float* sumw  = (float*)take((long)MM*4);
    u16* hidden  = (u16*)take((long)MM*HH*2);

    // x_slot sub-layout (phase 2):
    u16* x_bf    = x_slot;
    u16* aiT     = x_slot;                         // 4*128*2048 = 1,048,576 u16
    u16* wRaw    = aiT  + 1048576;                 // [Wp|Wap] raw: 2*2048*128 = 524,288
    u16* wT      = wRaw + 524288;                  // [WpT|WapT]: 2*128*2048 = 524,288
    u16* wpost_w = wT   + 524288;                  // 128*2048 = 262,144
    u16* wcat    = wpost_w + 262144;               // 1024*256 = 262,144
    u16* ao_bf   = wcat + 262144;                  // 8192*128 = 1,048,576
    float* wcP   = (float*)(ao_bf + 1048576);      // 2*4*1024*128 f32 = 4MB
    float* preP   = (float*)shareA;
    float* wpostP = (float*)shareA;

    // 1. converts phase 1: x, Wu, Wg, Wpre, Aex
    {
        Cvt5 a;
        a.in[0]=x;    a.out[0]=x_bf;            long n0=(long)MM*DD/4;
        a.in[1]=Wu;   a.out[1]=wslot;           long n1=(long)HH*DD/4;
        a.in[2]=Wg;   a.out[2]=wslot+(long)DD*HH; long n2=(long)HH*DD/4;
        a.in[3]=Wpre; a.out[3]=wpre;            long n3=(long)AD*DD/4;
        a.in[4]=Aex;  a.out[4]=aex;             long n4=(long)EE*AD*AD/4;
        a.cum[0]=0; a.cum[1]=n0; a.cum[2]=n0+n1; a.cum[3]=n0+n1+n2;
        a.cum[4]=n0+n1+n2+n3; a.cum[5]=n0+n1+n2+n3+n4;
        cvt_pack<<<dim3((a.cum[5]+255)/256), 256, 0, stream>>>(a);
    }
    // 2. pre partials: x @ Wpre^T, split-K S=4
    mfma_sk<<<dim3(4, MM/128, 1), 256, 0, stream>>>(
        x_bf, wpre, preP, MM, DD, 4, 0, 0, 0, (long)MM*AD);
    // 3. reduce + bpre -> pre_bf (raw) and ai_bf (LN)
    ln_reduce<4><<<dim3(MM), 128, 0, stream>>>(preP, (long)MM*AD, bpre, pre_bf, ai_bf, ln_g, ln_b);
    // 4. fused expert branch -> acat[:,0:128], sumw
    expert_fused<<<dim3(MM/128), 256, 0, stream>>>(pre_bf, aex, ew, eg, eb, acat, sumw);
    // 5. hidden = bf16(silu(x@Wg^T+bg)*(x@Wu^T+bu))
    mfma_upgate<<<dim3(HH/128, MM/128, 1), 256, 0, stream>>>(
        x_bf, wslot, wslot+(long)DD*HH, bu, bg, hidden);
    // 6. converts phase 2: Wo, Wd, Wpost, Wp, Wap  (x_bf/Wu/Wg dead)
    {
        Cvt5 a;
        a.in[0]=Wo;    a.out[0]=wslot;             long n0=(long)DD*HH/4;
        a.in[1]=Wd;    a.out[1]=wslot+(long)DD*HH; long n1=(long)DD*HH/4;
        a.in[2]=Wpost; a.out[2]=wpost_w;           long n2=(long)AD*HH/4;
        a.in[3]=Wp;    a.out[3]=wRaw;              long n3=(long)HH*AD/4;
        a.in[4]=Wap;   a.out[4]=wRaw+(long)HH*AD;  long n4=(long)HH*AD/4;
        a.cum[0]=0; a.cum[1]=n0; a.cum[2]=n0+n1; a.cum[3]=n0+n1+n2;
        a.cum[4]=n0+n1+n2+n3; a.cum[5]=n0+n1+n2+n3+n4;
        cvt_pack<<<dim3((a.cum[5]+255)/256), 256, 0, stream>>>(a);
    }
    // 7. [WpT|WapT] = transpose([Wp|Wap]), z=2
    transpose_bf<<<dim3(4,64,2), 256, 0, stream>>>(wRaw, wT, (long)HH*AD, (long)AD*HH);
    // 8. Wc=Wo@Wp, Wdap=Wd@Wap: split-K S=4, z=2
    mfma_sk<<<dim3(4, DD/128, 2), 256, 0, stream>>>(
        wslot, wT, wcP, DD, HH, 4, (long)DD*HH, (long)AD*HH, 4L*DD*AD, (long)DD*AD);
    // 9. Wcat[d, 0:128]=Wc, [128:256]=Wdap
    reduce_cat<<<dim3(256), 256, 0, stream>>>(wcP, wcat);
    // 10. hidden @ Wpost^T partials, split-K S=8
    mfma_sk<<<dim3(8, MM/128, 1), 256, 0, stream>>>(
        hidden, wpost_w, wpostP, MM, HH, 8, 0, 0, 0, (long)MM*AD);
    // 11. ao_bf = LN(. + bpost)
    ln_reduce<8><<<dim3(MM), 128, 0, stream>>>(wpostP, (long)MM*AD, bpost, nullptr, ao_bf, ln_g, ln_b);
    // 12. aiT[b] = ai[b]^T
    transpose_bf<<<dim3(4,64,4), 256, 0, stream>>>(ai_bf, aiT, (long)SS*AD, (long)AD*SS);
    // 13. flash: acat[:,128:256] = sumw * (silu(clip(ai@ao^T)) @ ai)
    flash_adapt<<<dim3(SS/64, BB), 256, 0, stream>>>(ai_bf, ao_bf, aiT, sumw, acat);
    // 14. out = sumw*(hidden@Wd^T + bd) + 0.1*(acat@Wcat^T)
    mfma_final<<<dim3(DD/128, MM/128), 256, 0, stream>>>(
        hidden, wslot+(long)DD*HH, acat, wcat, bd, sumw, out);
}

// Round 5
// 439.548 us; speedup vs baseline: 1.0773x; 1.0773x over previous
//
#include <hip/hip_runtime.h>
#include <math.h>

// Problem constants
#define BB 4
#define SS 2048
#define DD 1024
#define HH 2048
#define AD 128
#define EE 8
#define MM (BB*SS)   // 8192

typedef unsigned short u16;
typedef short bf16x8 __attribute__((ext_vector_type(8)));
typedef float f32x4 __attribute__((ext_vector_type(4)));

__device__ __forceinline__ float silu_f(float x){ return x / (1.f + __expf(-x)); }

__device__ __forceinline__ u16 f2bf(float f){
    union { float f; unsigned u; } c; c.f = f;
    unsigned r = (c.u + 0x7FFFu + ((c.u >> 16) & 1u)) >> 16;
    return (u16)r;
}

// async global->LDS, 16B per lane. LDS dest must be wave-uniform base + lane*16.
__device__ __forceinline__ void gld16(const u16* g, u16* l){
    __builtin_amdgcn_global_load_lds((const __attribute__((address_space(1))) void*)g,
                                     (__attribute__((address_space(3))) void*)l, 16, 0, 0);
}

// ---------------------------------------------------------------------------
// NT bf16 MFMA GEMM: C[M,N] = epi(A[M,K] @ B[N,K]^T). 128x128 tile, BK=32.
// EPI: 2 bf16 store silu(clip(acc,-5,5))
// ---------------------------------------------------------------------------
template<int EPI>
__global__ __launch_bounds__(256,2) void mfma_nt(
    const u16* __restrict__ A, const u16* __restrict__ B, void* Cv,
    int M, int N, int K, long sA, long sB, long sC)
{
    __shared__ __align__(16) u16 As[128*32];
    __shared__ __align__(16) u16 Bs[128*32];
    const int t = threadIdx.x;
    const int lane = t & 63;
    const int wv = t >> 6;
    const int m0 = blockIdx.y * 128, n0 = blockIdx.x * 128;
    const u16* Ab = A + (long)blockIdx.z * sA;
    const u16* Bb = B + (long)blockIdx.z * sB;
    const int srow = t >> 2, scol = (t & 3) * 8;
    const u16* ga0 = Ab + (long)(m0 + srow) * K + scol;
    const u16* ga1 = ga0 + 64L * K;
    const u16* gb0 = Bb + (long)(n0 + srow) * K + scol;
    const u16* gb1 = gb0 + 64L * K;
    u16* la0 = As + t * 8;  u16* la1 = As + 2048 + t * 8;
    u16* lb0 = Bs + t * 8;  u16* lb1 = Bs + 2048 + t * 8;
    const int fr = lane & 15, q = lane >> 4;
    const int wm = (wv & 1) * 64, wn = (wv >> 1) * 64;

    f32x4 acc[4][4] = {};
    for (int k0 = 0; k0 < K; k0 += 32) {
        gld16(ga0 + k0, la0);
        gld16(ga1 + k0, la1);
        gld16(gb0 + k0, lb0);
        gld16(gb1 + k0, lb1);
        __syncthreads();
        bf16x8 af[4], bfr[4];
        #pragma unroll
        for (int i = 0; i < 4; ++i) af[i]  = *(const bf16x8*)&As[(wm + i*16 + fr)*32 + q*8];
        #pragma unroll
        for (int i = 0; i < 4; ++i) bfr[i] = *(const bf16x8*)&Bs[(wn + i*16 + fr)*32 + q*8];
        #pragma unroll
        for (int mi = 0; mi < 4; ++mi)
            #pragma unroll
            for (int ni = 0; ni < 4; ++ni)
                acc[mi][ni] = __builtin_amdgcn_mfma_f32_16x16x32_bf16(af[mi], bfr[ni], acc[mi][ni], 0, 0, 0);
        __syncthreads();
    }

    u16* Cb = (u16*)Cv + (long)blockIdx.z * sC;
    #pragma unroll
    for (int mi = 0; mi < 4; ++mi)
        #pragma unroll
        for (int ni = 0; ni < 4; ++ni) {
            const int col = n0 + wn + ni*16 + fr;
            #pragma unroll
            for (int r = 0; r < 4; ++r) {
                const int row = m0 + wm + mi*16 + q*4 + r;
                float v = acc[mi][ni][r];
                v = fminf(fmaxf(v, -5.f), 5.f);
                Cb[(long)row * N + col] = f2bf(silu_f(v));
            }
        }
}

// ---------------------------------------------------------------------------
// Split-K NT GEMM, N fixed = 128. grid = (S, M/128, Z).
// P offset = s*sSplit + z*sC.
// ---------------------------------------------------------------------------
__global__ __launch_bounds__(256,2) void mfma_sk(
    const u16* __restrict__ A, const u16* __restrict__ B, float* __restrict__ P,
    int M, int K, int S, long sA, long sB, long sC, long sSplit)
{
    __shared__ __align__(16) u16 As[128*32];
    __shared__ __align__(16) u16 Bs[128*32];
    const int t = threadIdx.x;
    const int lane = t & 63;
    const int wv = t >> 6;
    const int s = blockIdx.x;
    const int m0 = blockIdx.y * 128;
    const u16* Ab = A + (long)blockIdx.z * sA;
    const u16* Bb = B + (long)blockIdx.z * sB;
    const int srow = t >> 2, scol = (t & 3) * 8;
    const int Ks = K / S, kBeg = s * Ks;
    const u16* ga0 = Ab + (long)(m0 + srow) * K + scol + kBeg;
    const u16* ga1 = ga0 + 64L * K;
    const u16* gb0 = Bb + (long)srow * K + scol + kBeg;
    const u16* gb1 = gb0 + 64L * K;
    u16* la0 = As + t * 8;  u16* la1 = As + 2048 + t * 8;
    u16* lb0 = Bs + t * 8;  u16* lb1 = Bs + 2048 + t * 8;
    const int fr = lane & 15, q = lane >> 4;
    const int wm = (wv & 1) * 64, wn = (wv >> 1) * 64;

    f32x4 acc[4][4] = {};
    for (int k0 = 0; k0 < Ks; k0 += 32) {
        gld16(ga0 + k0, la0);
        gld16(ga1 + k0, la1);
        gld16(gb0 + k0, lb0);
        gld16(gb1 + k0, lb1);
        __syncthreads();
        bf16x8 af[4], bfr[4];
        #pragma unroll
        for (int i = 0; i < 4; ++i) af[i]  = *(const bf16x8*)&As[(wm + i*16 + fr)*32 + q*8];
        #pragma unroll
        for (int i = 0; i < 4; ++i) bfr[i] = *(const bf16x8*)&Bs[(wn + i*16 + fr)*32 + q*8];
        #pragma unroll
        for (int mi = 0; mi < 4; ++mi)
            #pragma unroll
            for (int ni = 0; ni < 4; ++ni)
                acc[mi][ni] = __builtin_amdgcn_mfma_f32_16x16x32_bf16(af[mi], bfr[ni], acc[mi][ni], 0, 0, 0);
        __syncthreads();
    }

    float* Pf = P + (long)s * sSplit + (long)blockIdx.z * sC;
    #pragma unroll
    for (int mi = 0; mi < 4; ++mi)
        #pragma unroll
        for (int ni = 0; ni < 4; ++ni) {
            const int col = wn + ni*16 + fr;
            #pragma unroll
            for (int r = 0; r < 4; ++r) {
                const int row = m0 + wm + mi*16 + q*4 + r;
                Pf[(long)row * 128 + col] = acc[mi][ni][r];
            }
        }
}

// ---------------------------------------------------------------------------
// Fused up/gate: H[M,HH] = bf16( silu(X@Wg^T+bg) * (X@Wu^T+bu) ). 128x128 tile.
// ---------------------------------------------------------------------------
__global__ __launch_bounds__(256,2) void mfma_upgate(
    const u16* __restrict__ X, const u16* __restrict__ Wu_, const u16* __restrict__ Wg_,
    const float* __restrict__ bu, const float* __restrict__ bg, u16* __restrict__ H)
{
    __shared__ __align__(16) u16 Xs[128*32];
    __shared__ __align__(16) u16 Us[128*32];
    __shared__ __align__(16) u16 Gs[128*32];
    const int t = threadIdx.x, lane = t & 63, wv = t >> 6;
    const int m0 = blockIdx.y * 128, n0 = blockIdx.x * 128;
    const int srow = t >> 2, scol = (t & 3) * 8;
    const u16* gx0 = X   + (long)(m0 + srow) * DD + scol;
    const u16* gx1 = gx0 + 64L * DD;
    const u16* gu0 = Wu_ + (long)(n0 + srow) * DD + scol;
    const u16* gu1 = gu0 + 64L * DD;
    const u16* gg0 = Wg_ + (long)(n0 + srow) * DD + scol;
    const u16* gg1 = gg0 + 64L * DD;
    const int fr = lane & 15, q = lane >> 4;
    const int wm = (wv & 1) * 64, wn = (wv >> 1) * 64;

    f32x4 accu[4][4] = {};
    f32x4 accg[4][4] = {};
    for (int k0 = 0; k0 < DD; k0 += 32) {
        gld16(gx0 + k0, Xs + t*8);
        gld16(gx1 + k0, Xs + 2048 + t*8);
        gld16(gu0 + k0, Us + t*8);
        gld16(gu1 + k0, Us + 2048 + t*8);
        gld16(gg0 + k0, Gs + t*8);
        gld16(gg1 + k0, Gs + 2048 + t*8);
        __syncthreads();
        bf16x8 xf[4], uf[4], gf[4];
        #pragma unroll
        for (int i = 0; i < 4; ++i) {
            xf[i] = *(const bf16x8*)&Xs[(wm + i*16 + fr)*32 + q*8];
            uf[i] = *(const bf16x8*)&Us[(wn + i*16 + fr)*32 + q*8];
            gf[i] = *(const bf16x8*)&Gs[(wn + i*16 + fr)*32 + q*8];
        }
        #pragma unroll
        for (int mi = 0; mi < 4; ++mi)
            #pragma unroll
            for (int ni = 0; ni < 4; ++ni) {
                accu[mi][ni] = __builtin_amdgcn_mfma_f32_16x16x32_bf16(xf[mi], uf[ni], accu[mi][ni], 0, 0, 0);
                accg[mi][ni] = __builtin_amdgcn_mfma_f32_16x16x32_bf16(xf[mi], gf[ni], accg[mi][ni], 0, 0, 0);
            }
        __syncthreads();
    }
    #pragma unroll
    for (int mi = 0; mi < 4; ++mi) {
        #pragma unroll
        for (int ni = 0; ni < 4; ++ni) {
            const int col = n0 + wn + ni*16 + fr;
            #pragma unroll
            for (int r = 0; r < 4; ++r) {
                const int row = m0 + wm + mi*16 + q*4 + r;
                const float u = accu[mi][ni][r] + bu[col];
                const float g = accg[mi][ni][r] + bg[col];
                H[(long)row * HH + col] = f2bf(silu_f(g) * u);
            }
        }
    }
}

// ---------------------------------------------------------------------------
// Final: out = sumw*(hidden@Wd^T + bd) + 0.1*(acat@Wcat^T). 128x128 tile.
// ---------------------------------------------------------------------------
__global__ __launch_bounds__(256,2) void mfma_final(
    const u16* __restrict__ Hh, const u16* __restrict__ Wd_,
    const u16* __restrict__ Ac, const u16* __restrict__ Wcat,
    const float* __restrict__ bd, const float* __restrict__ sumw,
    float* __restrict__ out)
{
    __shared__ __align__(16) u16 As[128*32];
    __shared__ __align__(16) u16 Bs[128*32];
    const int t = threadIdx.x, lane = t & 63, wv = t >> 6;
    const int m0 = blockIdx.y * 128, n0 = blockIdx.x * 128;
    const int srow = t >> 2, scol = (t & 3) * 8;
    const int fr = lane & 15, q = lane >> 4;
    const int wm = (wv & 1) * 64, wn = (wv >> 1) * 64;
    u16* la0 = As + t * 8;  u16* la1 = As + 2048 + t * 8;
    u16* lb0 = Bs + t * 8;  u16* lb1 = Bs + 2048 + t * 8;

    f32x4 acc[4][4] = {};
    {
        const u16* ga0 = Hh  + (long)(m0 + srow) * HH + scol;
        const u16* ga1 = ga0 + 64L * HH;
        const u16* gb0 = Wd_ + (long)(n0 + srow) * HH + scol;
        const u16* gb1 = gb0 + 64L * HH;
        for (int k0 = 0; k0 < HH; k0 += 32) {
            gld16(ga0 + k0, la0);
            gld16(ga1 + k0, la1);
            gld16(gb0 + k0, lb0);
            gld16(gb1 + k0, lb1);
            __syncthreads();
            bf16x8 af[4], bfr[4];
            #pragma unroll
            for (int i = 0; i < 4; ++i) af[i]  = *(const bf16x8*)&As[(wm + i*16 + fr)*32 + q*8];
            #pragma unroll
            for (int i = 0; i < 4; ++i) bfr[i] = *(const bf16x8*)&Bs[(wn + i*16 + fr)*32 + q*8];
            #pragma unroll
            for (int mi = 0; mi < 4; ++mi)
                #pragma unroll
                for (int ni = 0; ni < 4; ++ni)
                    acc[mi][ni] = __builtin_amdgcn_mfma_f32_16x16x32_bf16(af[mi], bfr[ni], acc[mi][ni], 0, 0, 0);
            __syncthreads();
        }
    }
    f32x4 acc2[4][4] = {};
    {
        const u16* ga0 = Ac   + (long)(m0 + srow) * 256 + scol;
        const u16* ga1 = ga0 + 64L * 256;
        const u16* gb0 = Wcat + (long)(n0 + srow) * 256 + scol;
        const u16* gb1 = gb0 + 64L * 256;
        for (int k0 = 0; k0 < 256; k0 += 32) {
            gld16(ga0 + k0, la0);
            gld16(ga1 + k0, la1);
            gld16(gb0 + k0, lb0);
            gld16(gb1 + k0, lb1);
            __syncthreads();
            bf16x8 af[4], bfr[4];
            #pragma unroll
            for (int i = 0; i < 4; ++i) af[i]  = *(const bf16x8*)&As[(wm + i*16 + fr)*32 + q*8];
            #pragma unroll
            for (int i = 0; i < 4; ++i) bfr[i] = *(const bf16x8*)&Bs[(wn + i*16 + fr)*32 + q*8];
            #pragma unroll
            for (int mi = 0; mi < 4; ++mi)
                #pragma unroll
                for (int ni = 0; ni < 4; ++ni)
                    acc2[mi][ni] = __builtin_amdgcn_mfma_f32_16x16x32_bf16(af[mi], bfr[ni], acc2[mi][ni], 0, 0, 0);
            __syncthreads();
        }
    }
    #pragma unroll
    for (int mi = 0; mi < 4; ++mi)
        #pragma unroll
        for (int ni = 0; ni < 4; ++ni) {
            const int col = n0 + wn + ni*16 + fr;
            #pragma unroll
            for (int r = 0; r < 4; ++r) {
                const int row = m0 + wm + mi*16 + q*4 + r;
                out[(long)row * DD + col] =
                    sumw[row] * (acc[mi][ni][r] + bd[col]) + 0.1f * acc2[mi][ni][r];
            }
        }
}

// ---------------------------------------------------------------------------
// Fused expert branch, 64-row blocks (grid MM/64). Wave wv owns rows wv*16..+15.
// For e in 0..7: h = pre@A[e]^T (frags direct from global), LN (shfl), weighted sum.
// Writes acat[:,0:128] (bf16) and sumw.
// ---------------------------------------------------------------------------
__global__ __launch_bounds__(256) void expert_fused(
    const u16* __restrict__ pre, const u16* __restrict__ aexp,
    const float* __restrict__ ew, const float* __restrict__ eg,
    const float* __restrict__ eb, u16* __restrict__ acat,
    float* __restrict__ sumw)
{
    __shared__ float ewsh[64*8];
    __shared__ float egsh[8*128], ebsh[8*128];
    const int t = threadIdx.x, lane = t & 63, wv = t >> 6;
    const int fr = lane & 15, q = lane >> 4;
    const int wm = wv * 16;
    const int m0 = blockIdx.x * 64;
    if (t < 128) {
        const int row = t >> 1, j = (t & 1)*4;
        *(float4*)&ewsh[row*8+j] = *(const float4*)&ew[(long)(m0+row)*EE + j];
    }
    {   const int e = t >> 5, c = (t & 31)*4;
        *(float4*)&egsh[e*128+c] = *(const float4*)&eg[e*128+c];
        *(float4*)&ebsh[e*128+c] = *(const float4*)&eb[e*128+c]; }
    __syncthreads();

    f32x4 hwacc[8] = {};
    for (int e = 0; e < EE; ++e) {
        f32x4 acc[8] = {};
        const u16* Ae = aexp + (long)e * AD * AD;
        #pragma unroll
        for (int ks = 0; ks < 4; ++ks) {
            bf16x8 af, bfr[8];
            af = *(const bf16x8*)&pre[(long)(m0 + wm + fr)*AD + ks*32 + q*8];
            #pragma unroll
            for (int ni = 0; ni < 8; ++ni)
                bfr[ni] = *(const bf16x8*)&Ae[(long)(ni*16 + fr)*AD + ks*32 + q*8];
            #pragma unroll
            for (int ni = 0; ni < 8; ++ni)
                acc[ni] = __builtin_amdgcn_mfma_f32_16x16x32_bf16(af, bfr[ni], acc[ni], 0, 0, 0);
        }
        #pragma unroll
        for (int r = 0; r < 4; ++r) {
            float s = 0.f, s2 = 0.f;
            #pragma unroll
            for (int ni = 0; ni < 8; ++ni) { const float v = acc[ni][r]; s += v; s2 += v*v; }
            #pragma unroll
            for (int msk = 1; msk < 16; msk <<= 1) {
                s  += __shfl_xor(s,  msk, 64);
                s2 += __shfl_xor(s2, msk, 64);
            }
            const float mean = s * (1.f/128.f);
            const float var  = s2 * (1.f/128.f) - mean*mean;
            const float rs   = rsqrtf(var + 1e-5f);
            const int rowl = wm + q*4 + r;
            float w = ewsh[rowl*8 + e]; w = w > 0.f ? w : 0.f;
            #pragma unroll
            for (int ni = 0; ni < 8; ++ni) {
                const int col = ni*16 + fr;
                hwacc[ni][r] += w * ((acc[ni][r] - mean) * rs * egsh[e*128+col] + ebsh[e*128+col]);
            }
        }
    }
    #pragma unroll
    for (int r = 0; r < 4; ++r) {
        const int rowl = wm + q*4 + r;
        #pragma unroll
        for (int ni = 0; ni < 8; ++ni)
            acat[(long)(m0+rowl)*256 + ni*16 + fr] = f2bf(hwacc[ni][r]);
        if (fr == 0) {
            float sw = 0.f;
            #pragma unroll
            for (int j = 0; j < 8; ++j) sw += ewsh[rowl*8 + j];
            sumw[m0 + rowl] = sw;
        }
    }
}

// ---------------------------------------------------------------------------
// Split-K reduce + bias + (optional raw bf16 out) + LayerNorm(128) -> bf16.
// ---------------------------------------------------------------------------
template<int S>
__global__ __launch_bounds__(128) void ln_reduce(
    const float* __restrict__ P, long sSplit, const float* __restrict__ bias,
    u16* __restrict__ raw, u16* __restrict__ ln_out,
    const float* __restrict__ g, const float* __restrict__ b)
{
    const int r = blockIdx.x, tid = threadIdx.x;
    float v = bias[tid];
    #pragma unroll
    for (int s = 0; s < S; ++s) v += P[(long)s * sSplit + (long)r * AD + tid];
    if (raw) raw[(long)r * AD + tid] = f2bf(v);
    __shared__ float red[AD], red2[AD];
    red[tid] = v; red2[tid] = v*v;
    __syncthreads();
    for (int s = 64; s > 0; s >>= 1) {
        if (tid < s) { red[tid] += red[tid+s]; red2[tid] += red2[tid+s]; }
        __syncthreads();
    }
    const float mean = red[0] * (1.f/AD);
    const float var  = red2[0] * (1.f/AD) - mean*mean;
    const float rs   = rsqrtf(var + 1e-5f);
    ln_out[(long)r * AD + tid] = f2bf((v - mean) * rs * g[tid] + b[tid]);
}

// Reduce wc partials (S=4, z=2) -> Wcat [1024, 256] bf16.
__global__ __launch_bounds__(256) void reduce_cat(
    const float* __restrict__ P, u16* __restrict__ Wcat)
{
    const int i = blockIdx.x * 256 + threadIdx.x;   // 65536 total
    const int a4 = i & 31, z = (i >> 5) & 1, d = i >> 6;
    const float* src = P + (long)z * (4L*DD*AD) + (long)d * AD + a4*4;
    float4 v = *(const float4*)src;
    #pragma unroll
    for (int s = 1; s < 4; ++s) {
        const float4 w = *(const float4*)(src + (long)s * DD * AD);
        v.x += w.x; v.y += w.y; v.z += w.z; v.w += w.w;
    }
    ushort4 o; o.x=f2bf(v.x); o.y=f2bf(v.y); o.z=f2bf(v.z); o.w=f2bf(v.w);
    ((ushort4*)Wcat)[(long)d*64 + z*32 + a4] = o;
}

// Reduce adapt partials (S=2, z-major layout) * sumw -> acat[:,128:256] bf16.
__global__ __launch_bounds__(256) void reduce_adapt(
    const float* __restrict__ P, const float* __restrict__ sumw, u16* __restrict__ acat)
{
    const int i = blockIdx.x * 256 + threadIdx.x;   // MM*AD/4 = 262144 total
    const int perz = SS*AD/4;                       // 65536 float4 per (z,s)
    const int z = i / perz, local = i - z * perz;
    const float4* base = (const float4*)P + (long)z * 2 * perz;
    float4 v = base[local];
    const float4 w2 = base[local + perz];
    v.x += w2.x; v.y += w2.y; v.z += w2.z; v.w += w2.w;
    const long grow = i >> 5;
    const float sw = sumw[grow];
    ushort4 o;
    o.x = f2bf(sw*v.x); o.y = f2bf(sw*v.y); o.z = f2bf(sw*v.z); o.w = f2bf(sw*v.w);
    ((ushort4*)acat)[grow*64 + 32 + (i & 31)] = o;
}

// bf16 transpose: in [2048,128] -> out [128,2048], z-batched via strides.
__global__ __launch_bounds__(256) void transpose_bf(
    const u16* __restrict__ in, u16* __restrict__ out, long sIn, long sOut)
{
    __shared__ u16 tile[32][33];
    in  += (long)blockIdx.z * sIn;
    out += (long)blockIdx.z * sOut;
    const int x0 = blockIdx.x * 32, y0 = blockIdx.y * 32;
    const int tx = threadIdx.x & 31, ty = threadIdx.x >> 5;
    #pragma unroll
    for (int j = 0; j < 4; ++j)
        tile[ty + j*8][tx] = in[(long)(y0 + ty + j*8) * AD + x0 + tx];
    __syncthreads();
    #pragma unroll
    for (int j = 0; j < 4; ++j)
        out[(long)(x0 + ty + j*8) * SS + y0 + tx] = tile[tx][ty + j*8];
}

// Packed f32->bf16 convert: 5 segments, 4 elems/thread. cum[] in float4 units.
struct Cvt5 { const float* in[5]; u16* out[5]; long cum[6]; };
__global__ __launch_bounds__(256) void cvt_pack(Cvt5 a)
{
    const long i = (long)blockIdx.x * 256 + threadIdx.x;
    if (i >= a.cum[5]) return;
    int s = 0;
    while (i >= a.cum[s+1]) ++s;
    const long j = i - a.cum[s];
    const float4 v = ((const float4*)a.in[s])[j];
    ushort4 o;
    o.x = f2bf(v.x); o.y = f2bf(v.y); o.z = f2bf(v.z); o.w = f2bf(v.w);
    ((ushort4*)a.out[s])[j] = o;
}

extern "C" void kernel_launch(void* const* d_in, const int* in_sizes, int n_in,
                              void* d_out, int out_size, void* d_ws, size_t ws_size,
                              hipStream_t stream) {
    const float* x    = (const float*)d_in[0];
    const float* ew   = (const float*)d_in[1];
    const float* Wu   = (const float*)d_in[2];
    const float* bu   = (const float*)d_in[3];
    const float* Wg   = (const float*)d_in[4];
    const float* bg   = (const float*)d_in[5];
    const float* Wd   = (const float*)d_in[6];
    const float* bd   = (const float*)d_in[7];
    const float* Wpre = (const float*)d_in[8];
    const float* bpre = (const float*)d_in[9];
    const float* Wpost= (const float*)d_in[10];
    const float* bpost= (const float*)d_in[11];
    const float* ln_g = (const float*)d_in[12];
    const float* ln_b = (const float*)d_in[13];
    const float* Wap  = (const float*)d_in[14];
    const float* Aex  = (const float*)d_in[15];
    const float* eg   = (const float*)d_in[16];
    const float* eb   = (const float*)d_in[17];
    const float* Wp   = (const float*)d_in[18];
    const float* Wo   = (const float*)d_in[19];
    float* out = (float*)d_out;

    // ---- workspace layout (~96.5 MB) ----
    char* p = (char*)d_ws;
    auto take = [&](long bytes) -> char* {
        char* r = p; p += (bytes + 255) & ~255L; return r;
    };
    u16* x_slot  = (u16*)take(16777216);          // x_bf phase1; sub-slots phase2
    u16* wslot   = (u16*)take((long)2*DD*HH*2);   // 8MB: [Wu|Wg] then [Wo|Wd]
    u16* wpre    = (u16*)take((long)AD*DD*2);
    u16* aex     = (u16*)take((long)EE*AD*AD*2);
    u16* pre_bf  = (u16*)take((long)MM*AD*2);
    u16* ai_bf   = (u16*)take((long)MM*AD*2);
    char* shareA = take(33554432);                // preP (16MB) / wpostP (32MB) / aw (32MB)
    u16* acat    = (u16*)take((long)MM*256*2);    // [hw | sumw*adapt]
    float* sumw  = (float*)take((long)MM*4);
    u16* hidden  = (u16*)take((long)MM*HH*2);

    // x_slot sub-layout (phase 2):
    u16* x_bf    = x_slot;
    u16* aiT     = x_slot;                         // 4*128*2048 = 1,048,576 u16
    u16* wRaw    = aiT  + 1048576;                 // [Wp|Wap]: 524,288
    u16* wT      = wRaw + 524288;                  // [WpT|WapT]: 524,288
    u16* wpost_w = wT   + 524288;                  // 262,144
    u16* wcat    = wpost_w + 262144;               // 262,144
    u16* ao_bf   = wcat + 262144;                  // 1,048,576
    float* wcP   = (float*)(ao_bf + 1048576);      // 4MB (dead after reduce_cat)
    float* awaiP = (float*)wcP;                    // 8MB (wcP 4MB + 5MB tail) for adapt partials
    float* preP   = (float*)shareA;
    float* wpostP = (float*)shareA;
    u16*   aw     = (u16*)shareA;                  // 4 x SS*SS bf16 = 32MB

    // 1. converts phase 1: x, Wu, Wg, Wpre, Aex
    {
        Cvt5 a;
        a.in[0]=x;    a.out[0]=x_bf;              long n0=(long)MM*DD/4;
        a.in[1]=Wu;   a.out[1]=wslot;             long n1=(long)HH*DD/4;
        a.in[2]=Wg;   a.out[2]=wslot+(long)DD*HH; long n2=(long)HH*DD/4;
        a.in[3]=Wpre; a.out[3]=wpre;              long n3=(long)AD*DD/4;
        a.in[4]=Aex;  a.out[4]=aex;               long n4=(long)EE*AD*AD/4;
        a.cum[0]=0; a.cum[1]=n0; a.cum[2]=n0+n1; a.cum[3]=n0+n1+n2;
        a.cum[4]=n0+n1+n2+n3; a.cum[5]=n0+n1+n2+n3+n4;
        cvt_pack<<<dim3((a.cum[5]+255)/256), 256, 0, stream>>>(a);
    }
    // 2. pre partials: x @ Wpre^T, split-K S=4
    mfma_sk<<<dim3(4, MM/128, 1), 256, 0, stream>>>(
        x_bf, wpre, preP, MM, DD, 4, 0, 0, 0, (long)MM*AD);
    // 3. reduce + bpre -> pre_bf (raw) and ai_bf (LN)
    ln_reduce<4><<<dim3(MM), 128, 0, stream>>>(preP, (long)MM*AD, bpre, pre_bf, ai_bf, ln_g, ln_b);
    // 4. fused expert branch -> acat[:,0:128], sumw
    expert_fused<<<dim3(MM/64), 256, 0, stream>>>(pre_bf, aex, ew, eg, eb, acat, sumw);
    // 5. hidden = bf16(silu(x@Wg^T+bg)*(x@Wu^T+bu))
    mfma_upgate<<<dim3(HH/128, MM/128, 1), 256, 0, stream>>>(
        x_bf, wslot, wslot+(long)DD*HH, bu, bg, hidden);
    // 6. converts phase 2: Wo, Wd, Wpost, Wp, Wap  (x_bf/Wu/Wg dead)
    {
        Cvt5 a;
        a.in[0]=Wo;    a.out[0]=wslot;             long n0=(long)DD*HH/4;
        a.in[1]=Wd;    a.out[1]=wslot+(long)DD*HH; long n1=(long)DD*HH/4;
        a.in[2]=Wpost; a.out[2]=wpost_w;           long n2=(long)AD*HH/4;
        a.in[3]=Wp;    a.out[3]=wRaw;              long n3=(long)HH*AD/4;
        a.in[4]=Wap;   a.out[4]=wRaw+(long)HH*AD;  long n4=(long)HH*AD/4;
        a.cum[0]=0; a.cum[1]=n0; a.cum[2]=n0+n1; a.cum[3]=n0+n1+n2;
        a.cum[4]=n0+n1+n2+n3; a.cum[5]=n0+n1+n2+n3+n4;
        cvt_pack<<<dim3((a.cum[5]+255)/256), 256, 0, stream>>>(a);
    }
    // 7. [WpT|WapT] = transpose([Wp|Wap]), z=2
    transpose_bf<<<dim3(4,64,2), 256, 0, stream>>>(wRaw, wT, (long)HH*AD, (long)AD*HH);
    // 8. Wc=Wo@Wp, Wdap=Wd@Wap: split-K S=4, z=2
    mfma_sk<<<dim3(4, DD/128, 2), 256, 0, stream>>>(
        wslot, wT, wcP, DD, HH, 4, (long)DD*HH, (long)AD*HH, 4L*DD*AD, (long)DD*AD);
    // 9. Wcat[d, 0:128]=Wc, [128:256]=Wdap
    reduce_cat<<<dim3(256), 256, 0, stream>>>(wcP, wcat);
    // 10. hidden @ Wpost^T partials, split-K S=8
    mfma_sk<<<dim3(8, MM/128, 1), 256, 0, stream>>>(
        hidden, wpost_w, wpostP, MM, HH, 8, 0, 0, 0, (long)MM*AD);
    // 11. ao_bf = LN(. + bpost)
    ln_reduce<8><<<dim3(MM), 128, 0, stream>>>(wpostP, (long)MM*AD, bpost, nullptr, ao_bf, ln_g, ln_b);
    // 12. aiT[b] = ai[b]^T
    transpose_bf<<<dim3(4,64,4), 256, 0, stream>>>(ai_bf, aiT, (long)SS*AD, (long)AD*SS);
    // 13. aw[b] = bf16(silu(clip(ai @ ao^T)))   (shareA free: wpostP consumed)
    mfma_nt<2><<<dim3(SS/128, SS/128, BB), 256, 0, stream>>>(ai_bf, ao_bf, aw,
        SS, SS, AD, (long)SS*AD, (long)SS*AD, (long)SS*SS);
    // 14. adapt partials: aw @ aiT^T, split-K S=2, z=4
    mfma_sk<<<dim3(2, SS/128, BB), 256, 0, stream>>>(
        aw, aiT, awaiP, SS, SS, 2, (long)SS*SS, (long)AD*SS, 2L*SS*AD, (long)SS*AD);
    // 15. acat[:,128:256] = bf16(sumw * (P0+P1))
    reduce_adapt<<<dim3((long)MM*AD/4/256), 256, 0, stream>>>(awaiP, sumw, acat);
    // 16. out = sumw*(hidden@Wd^T + bd) + 0.1*(acat@Wcat^T)
    mfma_final<<<dim3(DD/128, MM/128), 256, 0, stream>>>(
        hidden, wslot+(long)DD*HH, acat, wcat, bd, sumw, out);
}

// Round 6
// 436.654 us; speedup vs baseline: 1.0845x; 1.0066x over previous
//
#include <hip/hip_runtime.h>
#include <math.h>

// Problem constants
#define BB 4
#define SS 2048
#define DD 1024
#define HH 2048
#define AD 128
#define EE 8
#define MM (BB*SS)   // 8192
#define PS 136       // Psh row stride (u16): 272B, 16B-aligned

typedef unsigned short u16;
typedef short bf16x8 __attribute__((ext_vector_type(8)));
typedef float f32x4 __attribute__((ext_vector_type(4)));
typedef float f32x16 __attribute__((ext_vector_type(16)));

__device__ __forceinline__ float silu_f(float x){ return x / (1.f + __expf(-x)); }

__device__ __forceinline__ u16 f2bf(float f){
    union { float f; unsigned u; } c; c.f = f;
    unsigned r = (c.u + 0x7FFFu + ((c.u >> 16) & 1u)) >> 16;
    return (u16)r;
}

// async global->LDS, 16B per lane. LDS dest must be wave-uniform base + lane*16.
__device__ __forceinline__ void gld16(const u16* g, u16* l){
    __builtin_amdgcn_global_load_lds((const __attribute__((address_space(1))) void*)g,
                                     (__attribute__((address_space(3))) void*)l, 16, 0, 0);
}

// ---------------------------------------------------------------------------
// Split-K NT GEMM (16x16x32), N fixed = 128. grid = (S, M/128, Z).
// ---------------------------------------------------------------------------
__global__ __launch_bounds__(256,2) void mfma_sk(
    const u16* __restrict__ A, const u16* __restrict__ B, float* __restrict__ P,
    int M, int K, int S, long sA, long sB, long sC, long sSplit)
{
    __shared__ __align__(16) u16 As[128*32];
    __shared__ __align__(16) u16 Bs[128*32];
    const int t = threadIdx.x;
    const int lane = t & 63;
    const int wv = t >> 6;
    const int s = blockIdx.x;
    const int m0 = blockIdx.y * 128;
    const u16* Ab = A + (long)blockIdx.z * sA;
    const u16* Bb = B + (long)blockIdx.z * sB;
    const int srow = t >> 2, scol = (t & 3) * 8;
    const int Ks = K / S, kBeg = s * Ks;
    const u16* ga0 = Ab + (long)(m0 + srow) * K + scol + kBeg;
    const u16* ga1 = ga0 + 64L * K;
    const u16* gb0 = Bb + (long)srow * K + scol + kBeg;
    const u16* gb1 = gb0 + 64L * K;
    u16* la0 = As + t * 8;  u16* la1 = As + 2048 + t * 8;
    u16* lb0 = Bs + t * 8;  u16* lb1 = Bs + 2048 + t * 8;
    const int fr = lane & 15, q = lane >> 4;
    const int wm = (wv & 1) * 64, wn = (wv >> 1) * 64;

    f32x4 acc[4][4] = {};
    for (int k0 = 0; k0 < Ks; k0 += 32) {
        gld16(ga0 + k0, la0);
        gld16(ga1 + k0, la1);
        gld16(gb0 + k0, lb0);
        gld16(gb1 + k0, lb1);
        __syncthreads();
        bf16x8 af[4], bfr[4];
        #pragma unroll
        for (int i = 0; i < 4; ++i) af[i]  = *(const bf16x8*)&As[(wm + i*16 + fr)*32 + q*8];
        #pragma unroll
        for (int i = 0; i < 4; ++i) bfr[i] = *(const bf16x8*)&Bs[(wn + i*16 + fr)*32 + q*8];
        #pragma unroll
        for (int mi = 0; mi < 4; ++mi)
            #pragma unroll
            for (int ni = 0; ni < 4; ++ni)
                acc[mi][ni] = __builtin_amdgcn_mfma_f32_16x16x32_bf16(af[mi], bfr[ni], acc[mi][ni], 0, 0, 0);
        __syncthreads();
    }

    float* Pf = P + (long)s * sSplit + (long)blockIdx.z * sC;
    #pragma unroll
    for (int mi = 0; mi < 4; ++mi)
        #pragma unroll
        for (int ni = 0; ni < 4; ++ni) {
            const int col = wn + ni*16 + fr;
            #pragma unroll
            for (int r = 0; r < 4; ++r) {
                const int row = m0 + wm + mi*16 + q*4 + r;
                Pf[(long)row * 128 + col] = acc[mi][ni][r];
            }
        }
}

// ---------------------------------------------------------------------------
// Fused up/gate, 32x32x16 MFMA: H = bf16(silu(X@Wg^T+bg)*(X@Wu^T+bu)).
// 128x128 tile, BK=32. Wave tile 64x64 = 2x2 of 32x32.
// ---------------------------------------------------------------------------
__global__ __launch_bounds__(256,2) void mfma_upgate(
    const u16* __restrict__ X, const u16* __restrict__ Wu_, const u16* __restrict__ Wg_,
    const float* __restrict__ bu, const float* __restrict__ bg, u16* __restrict__ H)
{
    __shared__ __align__(16) u16 Xs[128*32];
    __shared__ __align__(16) u16 Us[128*32];
    __shared__ __align__(16) u16 Gs[128*32];
    const int t = threadIdx.x, lane = t & 63, wv = t >> 6;
    const int m0 = blockIdx.y * 128, n0 = blockIdx.x * 128;
    const int srow = t >> 2, scol = (t & 3) * 8;
    const u16* gx0 = X   + (long)(m0 + srow) * DD + scol;
    const u16* gx1 = gx0 + 64L * DD;
    const u16* gu0 = Wu_ + (long)(n0 + srow) * DD + scol;
    const u16* gu1 = gu0 + 64L * DD;
    const u16* gg0 = Wg_ + (long)(n0 + srow) * DD + scol;
    const u16* gg1 = gg0 + 64L * DD;
    const int l31 = lane & 31, kh = lane >> 5;
    const int wm = (wv & 1) * 64, wn = (wv >> 1) * 64;

    f32x16 accu[2][2] = {};
    f32x16 accg[2][2] = {};
    for (int k0 = 0; k0 < DD; k0 += 32) {
        gld16(gx0 + k0, Xs + t*8);
        gld16(gx1 + k0, Xs + 2048 + t*8);
        gld16(gu0 + k0, Us + t*8);
        gld16(gu1 + k0, Us + 2048 + t*8);
        gld16(gg0 + k0, Gs + t*8);
        gld16(gg1 + k0, Gs + 2048 + t*8);
        __syncthreads();
        bf16x8 xf[2][2], uf[2][2], gf[2][2];
        #pragma unroll
        for (int mt = 0; mt < 2; ++mt)
            #pragma unroll
            for (int ks = 0; ks < 2; ++ks) {
                xf[mt][ks] = *(const bf16x8*)&Xs[(wm + mt*32 + l31)*32 + ks*16 + kh*8];
                uf[mt][ks] = *(const bf16x8*)&Us[(wn + mt*32 + l31)*32 + ks*16 + kh*8];
                gf[mt][ks] = *(const bf16x8*)&Gs[(wn + mt*32 + l31)*32 + ks*16 + kh*8];
            }
        #pragma unroll
        for (int mt = 0; mt < 2; ++mt)
            #pragma unroll
            for (int nt = 0; nt < 2; ++nt)
                #pragma unroll
                for (int ks = 0; ks < 2; ++ks) {
                    accu[mt][nt] = __builtin_amdgcn_mfma_f32_32x32x16_bf16(xf[mt][ks], uf[nt][ks], accu[mt][nt], 0, 0, 0);
                    accg[mt][nt] = __builtin_amdgcn_mfma_f32_32x32x16_bf16(xf[mt][ks], gf[nt][ks], accg[mt][nt], 0, 0, 0);
                }
        __syncthreads();
    }
    #pragma unroll
    for (int mt = 0; mt < 2; ++mt)
        #pragma unroll
        for (int nt = 0; nt < 2; ++nt) {
            const int col = n0 + wn + nt*32 + l31;
            #pragma unroll
            for (int r = 0; r < 16; ++r) {
                const int row = m0 + wm + mt*32 + (r & 3) + 8*(r >> 2) + 4*kh;
                const float u = accu[mt][nt][r] + bu[col];
                const float g = accg[mt][nt][r] + bg[col];
                H[(long)row * HH + col] = f2bf(silu_f(g) * u);
            }
        }
}

// ---------------------------------------------------------------------------
// Final, 32x32x16: out = sumw*(hidden@Wd^T + bd) + 0.1*(acat@Wcat^T).
// ---------------------------------------------------------------------------
__global__ __launch_bounds__(256,2) void mfma_final(
    const u16* __restrict__ Hh, const u16* __restrict__ Wd_,
    const u16* __restrict__ Ac, const u16* __restrict__ Wcat,
    const float* __restrict__ bd, const float* __restrict__ sumw,
    float* __restrict__ out)
{
    __shared__ __align__(16) u16 As[128*32];
    __shared__ __align__(16) u16 Bs[128*32];
    const int t = threadIdx.x, lane = t & 63, wv = t >> 6;
    const int m0 = blockIdx.y * 128, n0 = blockIdx.x * 128;
    const int srow = t >> 2, scol = (t & 3) * 8;
    const int l31 = lane & 31, kh = lane >> 5;
    const int wm = (wv & 1) * 64, wn = (wv >> 1) * 64;
    u16* la0 = As + t * 8;  u16* la1 = As + 2048 + t * 8;
    u16* lb0 = Bs + t * 8;  u16* lb1 = Bs + 2048 + t * 8;

    f32x16 acc[2][2] = {};
    {
        const u16* ga0 = Hh  + (long)(m0 + srow) * HH + scol;
        const u16* ga1 = ga0 + 64L * HH;
        const u16* gb0 = Wd_ + (long)(n0 + srow) * HH + scol;
        const u16* gb1 = gb0 + 64L * HH;
        for (int k0 = 0; k0 < HH; k0 += 32) {
            gld16(ga0 + k0, la0);
            gld16(ga1 + k0, la1);
            gld16(gb0 + k0, lb0);
            gld16(gb1 + k0, lb1);
            __syncthreads();
            bf16x8 af[2][2], bf[2][2];
            #pragma unroll
            for (int mt = 0; mt < 2; ++mt)
                #pragma unroll
                for (int ks = 0; ks < 2; ++ks) {
                    af[mt][ks] = *(const bf16x8*)&As[(wm + mt*32 + l31)*32 + ks*16 + kh*8];
                    bf[mt][ks] = *(const bf16x8*)&Bs[(wn + mt*32 + l31)*32 + ks*16 + kh*8];
                }
            #pragma unroll
            for (int mt = 0; mt < 2; ++mt)
                #pragma unroll
                for (int nt = 0; nt < 2; ++nt)
                    #pragma unroll
                    for (int ks = 0; ks < 2; ++ks)
                        acc[mt][nt] = __builtin_amdgcn_mfma_f32_32x32x16_bf16(af[mt][ks], bf[nt][ks], acc[mt][nt], 0, 0, 0);
            __syncthreads();
        }
    }
    f32x16 acc2[2][2] = {};
    {
        const u16* ga0 = Ac   + (long)(m0 + srow) * 256 + scol;
        const u16* ga1 = ga0 + 64L * 256;
        const u16* gb0 = Wcat + (long)(n0 + srow) * 256 + scol;
        const u16* gb1 = gb0 + 64L * 256;
        for (int k0 = 0; k0 < 256; k0 += 32) {
            gld16(ga0 + k0, la0);
            gld16(ga1 + k0, la1);
            gld16(gb0 + k0, lb0);
            gld16(gb1 + k0, lb1);
            __syncthreads();
            bf16x8 af[2][2], bf[2][2];
            #pragma unroll
            for (int mt = 0; mt < 2; ++mt)
                #pragma unroll
                for (int ks = 0; ks < 2; ++ks) {
                    af[mt][ks] = *(const bf16x8*)&As[(wm + mt*32 + l31)*32 + ks*16 + kh*8];
                    bf[mt][ks] = *(const bf16x8*)&Bs[(wn + mt*32 + l31)*32 + ks*16 + kh*8];
                }
            #pragma unroll
            for (int mt = 0; mt < 2; ++mt)
                #pragma unroll
                for (int nt = 0; nt < 2; ++nt)
                    #pragma unroll
                    for (int ks = 0; ks < 2; ++ks)
                        acc2[mt][nt] = __builtin_amdgcn_mfma_f32_32x32x16_bf16(af[mt][ks], bf[nt][ks], acc2[mt][nt], 0, 0, 0);
            __syncthreads();
        }
    }
    #pragma unroll
    for (int mt = 0; mt < 2; ++mt)
        #pragma unroll
        for (int nt = 0; nt < 2; ++nt) {
            const int col = n0 + wn + nt*32 + l31;
            #pragma unroll
            for (int r = 0; r < 16; ++r) {
                const int row = m0 + wm + mt*32 + (r & 3) + 8*(r >> 2) + 4*kh;
                out[(long)row * DD + col] =
                    sumw[row] * (acc[mt][nt][r] + bd[col]) + 0.1f * acc2[mt][nt][r];
            }
        }
}

// ---------------------------------------------------------------------------
// Flash with deterministic T-partials. grid = (8 t-groups, 16 s-tiles, 4 b).
// Per block: for 2 t-tiles: P = silu(clip(ai@ao^T)) (LDS-staged QK), P->Psh,
// vacc += P @ aiT. Store f32 partial slice adaptP[tg] (no atomics).
// ---------------------------------------------------------------------------
__global__ __launch_bounds__(256,2) void flash_pv(
    const u16* __restrict__ ai, const u16* __restrict__ ao,
    const u16* __restrict__ aiT, float* __restrict__ adaptP)
{
    __shared__ __align__(16) u16 As[128*32];
    __shared__ __align__(16) u16 Bs[128*32];
    __shared__ __align__(16) u16 Psh[128*PS];
    const int t = threadIdx.x, lane = t & 63, wv = t >> 6;
    const int fr = lane & 15, q = lane >> 4;
    const int wm = (wv & 1) * 64, wn = (wv >> 1) * 64;
    const int tg = blockIdx.x, s0 = blockIdx.y * 128, b = blockIdx.z;
    const u16* aib  = ai  + (long)b * SS * AD;
    const u16* aob  = ao  + (long)b * SS * AD;
    const u16* aiTb = aiT + (long)b * AD * SS;
    const int srow = t >> 2, scol = (t & 3) * 8;
    u16* la0 = As + t * 8;  u16* la1 = As + 2048 + t * 8;
    u16* lb0 = Bs + t * 8;  u16* lb1 = Bs + 2048 + t * 8;
    const u16* ga0 = aib + (long)(s0 + srow) * AD + scol;
    const u16* ga1 = ga0 + 64L * AD;

    f32x4 vacc[4][4] = {};
    for (int ti = 0; ti < 2; ++ti) {
        const int t0 = tg * 256 + ti * 128;
        const u16* gb0 = aob + (long)(t0 + srow) * AD + scol;
        const u16* gb1 = gb0 + 64L * AD;
        f32x4 acc[4][4] = {};
        for (int k0 = 0; k0 < AD; k0 += 32) {
            gld16(ga0 + k0, la0);
            gld16(ga1 + k0, la1);
            gld16(gb0 + k0, lb0);
            gld16(gb1 + k0, lb1);
            __syncthreads();
            bf16x8 af[4], bfr[4];
            #pragma unroll
            for (int i = 0; i < 4; ++i) af[i]  = *(const bf16x8*)&As[(wm + i*16 + fr)*32 + q*8];
            #pragma unroll
            for (int i = 0; i < 4; ++i) bfr[i] = *(const bf16x8*)&Bs[(wn + i*16 + fr)*32 + q*8];
            #pragma unroll
            for (int mi = 0; mi < 4; ++mi)
                #pragma unroll
                for (int ni = 0; ni < 4; ++ni)
                    acc[mi][ni] = __builtin_amdgcn_mfma_f32_16x16x32_bf16(af[mi], bfr[ni], acc[mi][ni], 0, 0, 0);
            __syncthreads();
        }
        // P -> Psh (bf16)
        #pragma unroll
        for (int mi = 0; mi < 4; ++mi)
            #pragma unroll
            for (int ni = 0; ni < 4; ++ni)
                #pragma unroll
                for (int r = 0; r < 4; ++r) {
                    float v = acc[mi][ni][r];
                    v = fminf(fmaxf(v, -5.f), 5.f);
                    Psh[(wm + mi*16 + q*4 + r)*PS + wn + ni*16 + fr] = f2bf(silu_f(v));
                }
        __syncthreads();
        // PV: vacc += Psh @ aiT-tile (B frags direct from global, L2-hot)
        #pragma unroll
        for (int kk = 0; kk < 4; ++kk) {
            bf16x8 pf[4], bi[4];
            #pragma unroll
            for (int mi = 0; mi < 4; ++mi)
                pf[mi] = *(const bf16x8*)&Psh[(wm + mi*16 + fr)*PS + kk*32 + q*8];
            #pragma unroll
            for (int ni = 0; ni < 4; ++ni)
                bi[ni] = *(const bf16x8*)&aiTb[(long)(wn + ni*16 + fr)*SS + t0 + kk*32 + q*8];
            #pragma unroll
            for (int mi = 0; mi < 4; ++mi)
                #pragma unroll
                for (int ni = 0; ni < 4; ++ni)
                    vacc[mi][ni] = __builtin_amdgcn_mfma_f32_16x16x32_bf16(pf[mi], bi[ni], vacc[mi][ni], 0, 0, 0);
        }
    }
    float* Pf = adaptP + (long)tg * MM * AD + (long)(b * SS + s0) * AD;
    #pragma unroll
    for (int mi = 0; mi < 4; ++mi)
        #pragma unroll
        for (int ni = 0; ni < 4; ++ni) {
            const int col = wn + ni*16 + fr;
            #pragma unroll
            for (int r = 0; r < 4; ++r) {
                const int row = wm + mi*16 + q*4 + r;
                Pf[(long)row * AD + col] = vacc[mi][ni][r];
            }
        }
}

// Sum 8 T-partials * sumw -> acat[:,128:256] bf16.
__global__ __launch_bounds__(256) void scale_adapt(
    const float* __restrict__ P, const float* __restrict__ sumw, u16* __restrict__ acat)
{
    const int i = blockIdx.x * 256 + threadIdx.x;   // MM*AD/4
    float4 v = ((const float4*)P)[i];
    #pragma unroll
    for (int tg = 1; tg < 8; ++tg) {
        const float4 w = ((const float4*)P)[i + (long)tg * (MM*AD/4)];
        v.x += w.x; v.y += w.y; v.z += w.z; v.w += w.w;
    }
    const long grow = i >> 5;
    const float sw = sumw[grow];
    ushort4 o;
    o.x = f2bf(sw*v.x); o.y = f2bf(sw*v.y); o.z = f2bf(sw*v.z); o.w = f2bf(sw*v.w);
    ((ushort4*)acat)[grow*64 + 32 + (i & 31)] = o;
}

// ---------------------------------------------------------------------------
// Fused expert branch, 64-row blocks (grid MM/64).
// ---------------------------------------------------------------------------
__global__ __launch_bounds__(256) void expert_fused(
    const u16* __restrict__ pre, const u16* __restrict__ aexp,
    const float* __restrict__ ew, const float* __restrict__ eg,
    const float* __restrict__ eb, u16* __restrict__ acat,
    float* __restrict__ sumw)
{
    __shared__ float ewsh[64*8];
    __shared__ float egsh[8*128], ebsh[8*128];
    const int t = threadIdx.x, lane = t & 63, wv = t >> 6;
    const int fr = lane & 15, q = lane >> 4;
    const int wm = wv * 16;
    const int m0 = blockIdx.x * 64;
    if (t < 128) {
        const int row = t >> 1, j = (t & 1)*4;
        *(float4*)&ewsh[row*8+j] = *(const float4*)&ew[(long)(m0+row)*EE + j];
    }
    {   const int e = t >> 5, c = (t & 31)*4;
        *(float4*)&egsh[e*128+c] = *(const float4*)&eg[e*128+c];
        *(float4*)&ebsh[e*128+c] = *(const float4*)&eb[e*128+c]; }
    __syncthreads();

    f32x4 hwacc[8] = {};
    for (int e = 0; e < EE; ++e) {
        f32x4 acc[8] = {};
        const u16* Ae = aexp + (long)e * AD * AD;
        #pragma unroll
        for (int ks = 0; ks < 4; ++ks) {
            bf16x8 af, bfr[8];
            af = *(const bf16x8*)&pre[(long)(m0 + wm + fr)*AD + ks*32 + q*8];
            #pragma unroll
            for (int ni = 0; ni < 8; ++ni)
                bfr[ni] = *(const bf16x8*)&Ae[(long)(ni*16 + fr)*AD + ks*32 + q*8];
            #pragma unroll
            for (int ni = 0; ni < 8; ++ni)
                acc[ni] = __builtin_amdgcn_mfma_f32_16x16x32_bf16(af, bfr[ni], acc[ni], 0, 0, 0);
        }
        #pragma unroll
        for (int r = 0; r < 4; ++r) {
            float s = 0.f, s2 = 0.f;
            #pragma unroll
            for (int ni = 0; ni < 8; ++ni) { const float v = acc[ni][r]; s += v; s2 += v*v; }
            #pragma unroll
            for (int msk = 1; msk < 16; msk <<= 1) {
                s  += __shfl_xor(s,  msk, 64);
                s2 += __shfl_xor(s2, msk, 64);
            }
            const float mean = s * (1.f/128.f);
            const float var  = s2 * (1.f/128.f) - mean*mean;
            const float rs   = rsqrtf(var + 1e-5f);
            const int rowl = wm + q*4 + r;
            float w = ewsh[rowl*8 + e]; w = w > 0.f ? w : 0.f;
            #pragma unroll
            for (int ni = 0; ni < 8; ++ni) {
                const int col = ni*16 + fr;
                hwacc[ni][r] += w * ((acc[ni][r] - mean) * rs * egsh[e*128+col] + ebsh[e*128+col]);
            }
        }
    }
    #pragma unroll
    for (int r = 0; r < 4; ++r) {
        const int rowl = wm + q*4 + r;
        #pragma unroll
        for (int ni = 0; ni < 8; ++ni)
            acat[(long)(m0+rowl)*256 + ni*16 + fr] = f2bf(hwacc[ni][r]);
        if (fr == 0) {
            float sw = 0.f;
            #pragma unroll
            for (int j = 0; j < 8; ++j) sw += ewsh[rowl*8 + j];
            sumw[m0 + rowl] = sw;
        }
    }
}

// ---------------------------------------------------------------------------
// Split-K reduce + bias + (optional raw bf16 out) + LayerNorm(128) -> bf16.
// ---------------------------------------------------------------------------
template<int S>
__global__ __launch_bounds__(128) void ln_reduce(
    const float* __restrict__ P, long sSplit, const float* __restrict__ bias,
    u16* __restrict__ raw, u16* __restrict__ ln_out,
    const float* __restrict__ g, const float* __restrict__ b)
{
    const int r = blockIdx.x, tid = threadIdx.x;
    float v = bias[tid];
    #pragma unroll
    for (int s = 0; s < S; ++s) v += P[(long)s * sSplit + (long)r * AD + tid];
    if (raw) raw[(long)r * AD + tid] = f2bf(v);
    __shared__ float red[AD], red2[AD];
    red[tid] = v; red2[tid] = v*v;
    __syncthreads();
    for (int s = 64; s > 0; s >>= 1) {
        if (tid < s) { red[tid] += red[tid+s]; red2[tid] += red2[tid+s]; }
        __syncthreads();
    }
    const float mean = red[0] * (1.f/AD);
    const float var  = red2[0] * (1.f/AD) - mean*mean;
    const float rs   = rsqrtf(var + 1e-5f);
    ln_out[(long)r * AD + tid] = f2bf((v - mean) * rs * g[tid] + b[tid]);
}

// Reduce wc partials (S=4, z=2) -> Wcat [1024, 256] bf16.
__global__ __launch_bounds__(256) void reduce_cat(
    const float* __restrict__ P, u16* __restrict__ Wcat)
{
    const int i = blockIdx.x * 256 + threadIdx.x;   // 65536 total
    const int a4 = i & 31, z = (i >> 5) & 1, d = i >> 6;
    const float* src = P + (long)z * (4L*DD*AD) + (long)d * AD + a4*4;
    float4 v = *(const float4*)src;
    #pragma unroll
    for (int s = 1; s < 4; ++s) {
        const float4 w = *(const float4*)(src + (long)s * DD * AD);
        v.x += w.x; v.y += w.y; v.z += w.z; v.w += w.w;
    }
    ushort4 o; o.x=f2bf(v.x); o.y=f2bf(v.y); o.z=f2bf(v.z); o.w=f2bf(v.w);
    ((ushort4*)Wcat)[(long)d*64 + z*32 + a4] = o;
}

// Combined bf16 transpose [2048,128]->[128,2048]: z<2: Wp/Wap; z>=2: ai batch z-2.
__global__ __launch_bounds__(256) void transpose6(
    const u16* __restrict__ wRaw, u16* __restrict__ wT,
    const u16* __restrict__ ai, u16* __restrict__ aiT)
{
    __shared__ u16 tile[32][33];
    const int z = blockIdx.z;
    const u16* in; u16* out;
    if (z < 2) { in = wRaw + (long)z * HH * AD; out = wT + (long)z * AD * HH; }
    else       { in = ai + (long)(z-2) * SS * AD; out = aiT + (long)(z-2) * AD * SS; }
    const int x0 = blockIdx.x * 32, y0 = blockIdx.y * 32;
    const int tx = threadIdx.x & 31, ty = threadIdx.x >> 5;
    #pragma unroll
    for (int j = 0; j < 4; ++j)
        tile[ty + j*8][tx] = in[(long)(y0 + ty + j*8) * AD + x0 + tx];
    __syncthreads();
    #pragma unroll
    for (int j = 0; j < 4; ++j)
        out[(long)(x0 + ty + j*8) * SS + y0 + tx] = tile[tx][ty + j*8];
}

// Packed f32->bf16 convert: 5 segments, 4 elems/thread. cum[] in float4 units.
struct Cvt5 { const float* in[5]; u16* out[5]; long cum[6]; };
__global__ __launch_bounds__(256) void cvt_pack(Cvt5 a)
{
    const long i = (long)blockIdx.x * 256 + threadIdx.x;
    if (i >= a.cum[5]) return;
    int s = 0;
    while (i >= a.cum[s+1]) ++s;
    const long j = i - a.cum[s];
    const float4 v = ((const float4*)a.in[s])[j];
    ushort4 o;
    o.x = f2bf(v.x); o.y = f2bf(v.y); o.z = f2bf(v.z); o.w = f2bf(v.w);
    ((ushort4*)a.out[s])[j] = o;
}

extern "C" void kernel_launch(void* const* d_in, const int* in_sizes, int n_in,
                              void* d_out, int out_size, void* d_ws, size_t ws_size,
                              hipStream_t stream) {
    const float* x    = (const float*)d_in[0];
    const float* ew   = (const float*)d_in[1];
    const float* Wu   = (const float*)d_in[2];
    const float* bu   = (const float*)d_in[3];
    const float* Wg   = (const float*)d_in[4];
    const float* bg   = (const float*)d_in[5];
    const float* Wd   = (const float*)d_in[6];
    const float* bd   = (const float*)d_in[7];
    const float* Wpre = (const float*)d_in[8];
    const float* bpre = (const float*)d_in[9];
    const float* Wpost= (const float*)d_in[10];
    const float* bpost= (const float*)d_in[11];
    const float* ln_g = (const float*)d_in[12];
    const float* ln_b = (const float*)d_in[13];
    const float* Wap  = (const float*)d_in[14];
    const float* Aex  = (const float*)d_in[15];
    const float* eg   = (const float*)d_in[16];
    const float* eb   = (const float*)d_in[17];
    const float* Wp   = (const float*)d_in[18];
    const float* Wo   = (const float*)d_in[19];
    float* out = (float*)d_out;

    // ---- workspace layout ----
    char* p = (char*)d_ws;
    auto take = [&](long bytes) -> char* {
        char* r = p; p += (bytes + 255) & ~255L; return r;
    };
    u16* x_slot  = (u16*)take(16777216);          // x_bf phase1; sub-slots phase2
    u16* wslot   = (u16*)take((long)2*DD*HH*2);   // 8MB: [Wu|Wg] then [Wo|Wd]
    u16* wpre    = (u16*)take((long)AD*DD*2);
    u16* aex     = (u16*)take((long)EE*AD*AD*2);
    u16* pre_bf  = (u16*)take((long)MM*AD*2);
    u16* ai_bf   = (u16*)take((long)MM*AD*2);
    char* shareA = take(33554432);                // preP(16MB)/wpostP(32MB)/adaptP(32MB)
    u16* acat    = (u16*)take((long)MM*256*2);    // [hw | sumw*adapt]
    float* sumw  = (float*)take((long)MM*4);
    u16* hidden  = (u16*)take((long)MM*HH*2);

    // x_slot sub-layout (phase 2):
    u16* x_bf    = x_slot;
    u16* aiT     = x_slot;                         // 4*128*2048 = 1,048,576 u16
    u16* wRaw    = aiT  + 1048576;                 // [Wp|Wap]: 524,288
    u16* wT      = wRaw + 524288;                  // [WpT|WapT]: 524,288
    u16* wpost_w = wT   + 524288;                  // 262,144
    u16* wcat    = wpost_w + 262144;               // 262,144
    u16* ao_bf   = wcat + 262144;                  // 1,048,576
    float* wcP   = (float*)(ao_bf + 1048576);      // 4MB (dead after reduce_cat)
    float* preP   = (float*)shareA;
    float* wpostP = (float*)shareA;
    float* adaptP = (float*)shareA;                // 8 x MM*AD f32 = 32MB

    // 1. converts phase 1: x, Wu, Wg, Wpre, Aex
    {
        Cvt5 a;
        a.in[0]=x;    a.out[0]=x_bf;              long n0=(long)MM*DD/4;
        a.in[1]=Wu;   a.out[1]=wslot;             long n1=(long)HH*DD/4;
        a.in[2]=Wg;   a.out[2]=wslot+(long)DD*HH; long n2=(long)HH*DD/4;
        a.in[3]=Wpre; a.out[3]=wpre;              long n3=(long)AD*DD/4;
        a.in[4]=Aex;  a.out[4]=aex;               long n4=(long)EE*AD*AD/4;
        a.cum[0]=0; a.cum[1]=n0; a.cum[2]=n0+n1; a.cum[3]=n0+n1+n2;
        a.cum[4]=n0+n1+n2+n3; a.cum[5]=n0+n1+n2+n3+n4;
        cvt_pack<<<dim3((a.cum[5]+255)/256), 256, 0, stream>>>(a);
    }
    // 2. pre partials: x @ Wpre^T, split-K S=4
    mfma_sk<<<dim3(4, MM/128, 1), 256, 0, stream>>>(
        x_bf, wpre, preP, MM, DD, 4, 0, 0, 0, (long)MM*AD);
    // 3. reduce + bpre -> pre_bf (raw) and ai_bf (LN)
    ln_reduce<4><<<dim3(MM), 128, 0, stream>>>(preP, (long)MM*AD, bpre, pre_bf, ai_bf, ln_g, ln_b);
    // 4. fused expert branch -> acat[:,0:128], sumw
    expert_fused<<<dim3(MM/64), 256, 0, stream>>>(pre_bf, aex, ew, eg, eb, acat, sumw);
    // 5. hidden = bf16(silu(x@Wg^T+bg)*(x@Wu^T+bu))
    mfma_upgate<<<dim3(HH/128, MM/128, 1), 256, 0, stream>>>(
        x_bf, wslot, wslot+(long)DD*HH, bu, bg, hidden);
    // 6. converts phase 2: Wo, Wd, Wpost, Wp, Wap  (x_bf/Wu/Wg dead)
    {
        Cvt5 a;
        a.in[0]=Wo;    a.out[0]=wslot;             long n0=(long)DD*HH/4;
        a.in[1]=Wd;    a.out[1]=wslot+(long)DD*HH; long n1=(long)DD*HH/4;
        a.in[2]=Wpost; a.out[2]=wpost_w;           long n2=(long)AD*HH/4;
        a.in[3]=Wp;    a.out[3]=wRaw;              long n3=(long)HH*AD/4;
        a.in[4]=Wap;   a.out[4]=wRaw+(long)HH*AD;  long n4=(long)HH*AD/4;
        a.cum[0]=0; a.cum[1]=n0; a.cum[2]=n0+n1; a.cum[3]=n0+n1+n2;
        a.cum[4]=n0+n1+n2+n3; a.cum[5]=n0+n1+n2+n3+n4;
        cvt_pack<<<dim3((a.cum[5]+255)/256), 256, 0, stream>>>(a);
    }
    // 7. transposes: [WpT|WapT] (z=0,1) and aiT per batch (z=2..5)
    transpose6<<<dim3(4,64,6), 256, 0, stream>>>(wRaw, wT, ai_bf, aiT);
    // 8. Wc=Wo@Wp, Wdap=Wd@Wap: split-K S=4, z=2
    mfma_sk<<<dim3(4, DD/128, 2), 256, 0, stream>>>(
        wslot, wT, wcP, DD, HH, 4, (long)DD*HH, (long)AD*HH, 4L*DD*AD, (long)DD*AD);
    // 9. Wcat[d, 0:128]=Wc, [128:256]=Wdap
    reduce_cat<<<dim3(256), 256, 0, stream>>>(wcP, wcat);
    // 10. hidden @ Wpost^T partials, split-K S=8
    mfma_sk<<<dim3(8, MM/128, 1), 256, 0, stream>>>(
        hidden, wpost_w, wpostP, MM, HH, 8, 0, 0, 0, (long)MM*AD);
    // 11. ao_bf = LN(. + bpost)
    ln_reduce<8><<<dim3(MM), 128, 0, stream>>>(wpostP, (long)MM*AD, bpost, nullptr, ao_bf, ln_g, ln_b);
    // 12. flash: adaptP[tg] = partial_t( silu(clip(ai@ao^T)) @ ai )
    flash_pv<<<dim3(8, SS/128, BB), 256, 0, stream>>>(ai_bf, ao_bf, aiT, adaptP);
    // 13. acat[:,128:256] = bf16(sumw * sum_tg adaptP)
    scale_adapt<<<dim3((long)MM*AD/4/256), 256, 0, stream>>>(adaptP, sumw, acat);
    // 14. out = sumw*(hidden@Wd^T + bd) + 0.1*(acat@Wcat^T)
    mfma_final<<<dim3(DD/128, MM/128), 256, 0, stream>>>(
        hidden, wslot+(long)DD*HH, acat, wcat, bd, sumw, out);
}